// Round 1
// baseline (1845.431 us; speedup 1.0000x reference)
//
#include <hip/hip_runtime.h>
#include <math.h>

#define BS 256
#define SCAN_CHUNK 2048
#define SCAN_ITEMS 8

// ---------------- dtype detection (edge_index int64 vs int32, mask u8 vs i32) ---------
__global__ void k_detect(const int* ei, const int* maskw, int* flags) {
  __shared__ int s_odd, s_maskhi;
  int t = threadIdx.x;
  if (t == 0) { s_odd = 0; s_maskhi = 0; }
  __syncthreads();
  int acc1 = 0;
  for (int i = t; i < 2048; i += blockDim.x) if (i & 1) acc1 |= ei[i];
  int acc2 = 0;
  for (int i = t; i < 256; i += blockDim.x) acc2 |= maskw[i] & 0xFFFFFF00;
  if (acc1) atomicOr(&s_odd, 1);
  if (acc2) atomicOr(&s_maskhi, 1);
  __syncthreads();
  if (t == 0) {
    flags[0] = (s_odd == 0) ? 1 : 0;     // 1 => edge_index stored as int64
    flags[1] = (s_maskhi == 0) ? 1 : 0;  // 1 => mask stored as int32, 0 => uint8
  }
}

__device__ __forceinline__ int ld_edge(const int* ei, int idx, int f64) {
  // little-endian: low word of int64 element idx is at word 2*idx
  return f64 ? ei[2 * (long long)idx] : ei[idx];
}

// ---------------- degree count ----------------
__global__ void k_count(const int* ei, int E, int* cnt, const int* flags) {
  int e = blockIdx.x * blockDim.x + threadIdx.x;
  if (e >= E) return;
  int f64 = flags[0];
  int dst = ld_edge(ei, E + e, f64);
  atomicAdd(&cnt[dst], 1);
}

__global__ void k_dinv(const int* cnt, int N, float* dinv, float* dinv_cs) {
  int n = blockIdx.x * blockDim.x + threadIdx.x;
  if (n >= N) return;
  float c = (float)cnt[n];
  dinv[n] = 1.0f / sqrtf(c + 1.0f);
  dinv_cs[n] = (cnt[n] > 0) ? (1.0f / sqrtf(c)) : 0.0f;
}

// ---------------- exclusive prefix scan over cnt -> rowptr ----------------
__global__ void k_scan1(const int* cnt, int N, int* excl, int* bsum) {
  __shared__ int s[BS];
  int b = blockIdx.x, t = threadIdx.x;
  int base = b * SCAN_CHUNK + t * SCAN_ITEMS;
  int v[SCAN_ITEMS];
  int tsum = 0;
#pragma unroll
  for (int i = 0; i < SCAN_ITEMS; i++) {
    int idx = base + i;
    v[i] = (idx < N) ? cnt[idx] : 0;
    tsum += v[i];
  }
  s[t] = tsum;
  __syncthreads();
  for (int d = 1; d < BS; d <<= 1) {
    int add = (t >= d) ? s[t - d] : 0;
    __syncthreads();
    s[t] += add;
    __syncthreads();
  }
  int incl = s[t];
  int texcl = incl - tsum;
  if (t == BS - 1) bsum[b] = incl;
  int run = texcl;
#pragma unroll
  for (int i = 0; i < SCAN_ITEMS; i++) {
    int idx = base + i;
    if (idx < N) excl[idx] = run;
    run += v[i];
  }
}

__global__ void k_scan2(int* bsum, int nb) {
  if (threadIdx.x == 0 && blockIdx.x == 0) {
    int run = 0;
    for (int i = 0; i < nb; i++) { int v = bsum[i]; bsum[i] = run; run += v; }
  }
}

__global__ void k_scan3(int* rowptr, const int* bsum, int N, int E) {
  int i = blockIdx.x * blockDim.x + threadIdx.x;
  if (i < N) rowptr[i] += bsum[i / SCAN_CHUNK];
  if (i == 0) rowptr[N] = E;
}

// ---------------- CSR fill: csr[j] = {src, bits(dinv_cs[src])} ----------------
__global__ void k_fill(const int* ei, int E, const int* rowptr, int* fill,
                       const float* dinv_cs, int2* csr, const int* flags) {
  int e = blockIdx.x * blockDim.x + threadIdx.x;
  if (e >= E) return;
  int f64 = flags[0];
  int s_ = ld_edge(ei, e, f64);
  int d_ = ld_edge(ei, E + e, f64);
  int pos = rowptr[d_] + atomicAdd(&fill[d_], 1);
  csr[pos] = make_int2(s_, __float_as_int(dinv_cs[s_]));
}

// ---------------- canonical mask ----------------
__global__ void k_mask(const void* maskp, const int* flags, int* mint, int N) {
  int n = blockIdx.x * blockDim.x + threadIdx.x;
  if (n >= N) return;
  int v = flags[1] ? ((const int*)maskp)[n] : (int)((const unsigned char*)maskp)[n];
  mint[n] = (v != 0) ? 1 : 0;
}

// ---------------- h0 = x @ W1 ----------------
__global__ void k_gemm1(const float* x, const float* W1, float* h0, int N) {
  __shared__ float Ws[64 * 64];
  __shared__ float xs[4][64];
  int t = threadIdx.x;
  for (int i = t; i < 4096; i += BS) Ws[i] = W1[i];
  int ty = t >> 6, c = t & 63;
  int row = blockIdx.x * 4 + ty;
  if (row < N) xs[ty][c] = x[row * 64 + c];
  __syncthreads();
  if (row >= N) return;
  float acc = 0.f;
#pragma unroll
  for (int k = 0; k < 64; k++) acc += xs[ty][k] * Ws[k * 64 + c];
  h0[row * 64 + c] = acc;
}

// ---------------- conv1: h = relu(gcn_conv(h0) + b1); g = h @ W2 (fused) --------------
__global__ void __launch_bounds__(64) k_conv1(const float* h0, const int2* csr, const int* rowptr,
                                              const float* dinv, const float* b1, const float* W2,
                                              float* g, int N) {
  int n = blockIdx.x;
  int c = threadIdx.x;
  int beg = rowptr[n], end = rowptr[n + 1];
  float acc = 0.f;
  for (int j = beg; j < end; j++) {
    int2 cw = csr[j];
    acc += dinv[cw.x] * h0[(long long)cw.x * 64 + c];
  }
  float dn = dinv[n];
  float val = dn * acc + dn * dn * h0[(long long)n * 64 + c] + b1[c];
  float hc = fmaxf(val, 0.f);
  float tsum = hc * W2[c];
  for (int off = 32; off > 0; off >>= 1) tsum += __shfl_down(tsum, off);
  if (c == 0) g[n] = tsum;
}

// ---------------- conv2 + sigmoid + error + seed ----------------
__global__ void k_conv2(const float* g, const int2* csr, const int* rowptr, const float* dinv,
                        const float* b2, const int* mint, const int* labels,
                        float2* probs, float2* error, float2* outA, int N) {
  int n = blockIdx.x * blockDim.x + threadIdx.x;
  if (n >= N) return;
  float s = 0.f;
  int beg = rowptr[n], end = rowptr[n + 1];
  for (int j = beg; j < end; j++) {
    int2 cw = csr[j];
    s += dinv[cw.x] * g[cw.x];
  }
  float dn = dinv[n];
  float logit = dn * s + dn * dn * g[n] + b2[0];
  float p = 1.f / (1.f + expf(-logit));
  float p0 = 1.f - p, p1 = p;
  probs[n] = make_float2(p0, p1);
  float e0 = 0.f, e1 = 0.f;
  if (mint[n]) {
    int lab = labels[n];
    e0 = (lab == 0 ? 1.f : 0.f) - p0;
    e1 = (lab == 1 ? 1.f : 0.f) - p1;
  }
  error[n] = make_float2(e0, e1);
  outA[n] = make_float2(e0, e1);
}

// ---------------- label prop 1 (alpha=0.5, fix) ----------------
__global__ void __launch_bounds__(BS) k_prop1(const float2* in, float2* out, const int2* csr,
                                              const int* rowptr, const float* dinv_cs,
                                              const float2* error, const int* mint, int N) {
  int n = blockIdx.x * blockDim.x + threadIdx.x;
  if (n >= N) return;
  if (mint[n]) { out[n] = error[n]; return; }
  float s0 = 0.f, s1 = 0.f;
  int beg = rowptr[n], end = rowptr[n + 1];
  for (int j = beg; j < end; j++) {
    int2 cw = csr[j];
    float w = __int_as_float(cw.y);
    float2 v = in[cw.x];
    s0 += w * v.x;
    s1 += w * v.y;
  }
  float a = 0.5f * dinv_cs[n];
  out[n] = make_float2(a * s0, a * s1);  // res = 0.5*error = 0 for unmasked nodes
}

// ---------------- y = where(m, onehot, probs + smoothed_error); seed out=y ------------
__global__ void k_y(const float2* probs, const float2* sm_err, const int* mint, const int* labels,
                    float2* y, float2* outSeed, int N) {
  int n = blockIdx.x * blockDim.x + threadIdx.x;
  if (n >= N) return;
  float2 v;
  if (mint[n]) {
    int lab = labels[n];
    v = make_float2(lab == 0 ? 1.f : 0.f, lab == 1 ? 1.f : 0.f);
  } else {
    float2 p = probs[n];
    float2 e = sm_err[n];
    v = make_float2(p.x + e.x, p.y + e.y);
  }
  y[n] = v;
  outSeed[n] = v;
}

// ---------------- label prop 2 (alpha=0.8, clamp) ----------------
__global__ void __launch_bounds__(BS) k_prop2(const float2* in, float2* out, const int2* csr,
                                              const int* rowptr, const float* dinv_cs,
                                              const float2* y, int N) {
  int n = blockIdx.x * blockDim.x + threadIdx.x;
  if (n >= N) return;
  float s0 = 0.f, s1 = 0.f;
  int beg = rowptr[n], end = rowptr[n + 1];
  for (int j = beg; j < end; j++) {
    int2 cw = csr[j];
    float w = __int_as_float(cw.y);
    float2 v = in[cw.x];
    s0 += w * v.x;
    s1 += w * v.y;
  }
  float a = 0.8f * dinv_cs[n];
  float2 yv = y[n];
  float o0 = a * s0 + 0.2f * yv.x;
  float o1 = a * s1 + 0.2f * yv.y;
  o0 = fminf(fmaxf(o0, 0.f), 1.f);
  o1 = fminf(fmaxf(o1, 0.f), 1.f);
  out[n] = make_float2(o0, o1);
}

__global__ void k_final(const float2* sm, float* out, int N) {
  int n = blockIdx.x * blockDim.x + threadIdx.x;
  if (n >= N) return;
  float2 v = sm[n];
  out[n] = logf(v.y + 1e-12f) - logf(v.x + 1e-12f);
}

// ---------------- host launcher ----------------
extern "C" void kernel_launch(void* const* d_in, const int* in_sizes, int n_in,
                              void* d_out, int out_size, void* d_ws, size_t ws_size,
                              hipStream_t stream) {
  const float* x = (const float*)d_in[0];
  const int* ei = (const int*)d_in[1];
  const void* maskp = d_in[2];
  const int* labels = (const int*)d_in[3];
  const float* W1 = (const float*)d_in[4];
  const float* b1 = (const float*)d_in[5];
  const float* W2 = (const float*)d_in[6];
  const float* b2 = (const float*)d_in[7];

  const int N = in_sizes[2];      // 100000
  const int E = in_sizes[1] / 2;  // 1600000

  // workspace carve (256B aligned)
  char* w = (char*)d_ws;
  auto alloc = [&](size_t bytes) -> void* {
    void* p = (void*)w;
    w += (bytes + 255) & ~(size_t)255;
    return p;
  };
  int* flags = (int*)alloc(8);
  int* cnt = (int*)alloc((size_t)N * 4);
  int* fill = (int*)alloc((size_t)N * 4);
  int* rowptr = (int*)alloc((size_t)(N + 1) * 4);
  int* bsum = (int*)alloc(256 * 4);
  int* mint = (int*)alloc((size_t)N * 4);
  float* dinv = (float*)alloc((size_t)N * 4);
  float* dinv_cs = (float*)alloc((size_t)N * 4);
  float* h0 = (float*)alloc((size_t)N * 64 * 4);
  float* g = (float*)alloc((size_t)N * 4);
  float2* probs = (float2*)alloc((size_t)N * 8);
  float2* error = (float2*)alloc((size_t)N * 8);
  float2* ybuf = (float2*)alloc((size_t)N * 8);
  float2* outA = (float2*)alloc((size_t)N * 8);
  float2* outB = (float2*)alloc((size_t)N * 8);
  int2* csr = (int2*)alloc((size_t)E * 8);

  const int gridN = (N + BS - 1) / BS;
  const int gridE = (E + BS - 1) / BS;
  const int nb = (N + SCAN_CHUNK - 1) / SCAN_CHUNK;

  hipMemsetAsync(cnt, 0, (size_t)N * 4, stream);
  hipMemsetAsync(fill, 0, (size_t)N * 4, stream);

  k_detect<<<1, 256, 0, stream>>>(ei, (const int*)maskp, flags);
  k_count<<<gridE, BS, 0, stream>>>(ei, E, cnt, flags);
  k_dinv<<<gridN, BS, 0, stream>>>(cnt, N, dinv, dinv_cs);
  k_scan1<<<nb, BS, 0, stream>>>(cnt, N, rowptr, bsum);
  k_scan2<<<1, 64, 0, stream>>>(bsum, nb);
  k_scan3<<<gridN, BS, 0, stream>>>(rowptr, bsum, N, E);
  k_fill<<<gridE, BS, 0, stream>>>(ei, E, rowptr, fill, dinv_cs, csr, flags);
  k_mask<<<gridN, BS, 0, stream>>>(maskp, flags, mint, N);

  k_gemm1<<<(N + 3) / 4, BS, 0, stream>>>(x, W1, h0, N);
  k_conv1<<<N, 64, 0, stream>>>(h0, csr, rowptr, dinv, b1, W2, g, N);
  k_conv2<<<gridN, BS, 0, stream>>>(g, csr, rowptr, dinv, b2, mint, labels, probs, error, outA, N);

  float2* pin = outA;
  float2* pout = outB;
  for (int it = 0; it < 50; it++) {
    k_prop1<<<gridN, BS, 0, stream>>>(pin, pout, csr, rowptr, dinv_cs, error, mint, N);
    float2* t = pin; pin = pout; pout = t;
  }
  // smoothed_error now in pin (outA after 50 swaps)
  k_y<<<gridN, BS, 0, stream>>>(probs, pin, mint, labels, ybuf, pin, N);
  for (int it = 0; it < 50; it++) {
    k_prop2<<<gridN, BS, 0, stream>>>(pin, pout, csr, rowptr, dinv_cs, ybuf, N);
    float2* t = pin; pin = pout; pout = t;
  }
  k_final<<<gridN, BS, 0, stream>>>(pin, (float*)d_out, N);
}

// Round 2
// 1348.776 us; speedup vs baseline: 1.3682x; 1.3682x over previous
//
#include <hip/hip_runtime.h>
#include <hip/hip_fp16.h>
#include <math.h>

#define BS 256
#define PBS 256
#define VEC 16
#define SCAN_CHUNK 2048
#define SCAN_ITEMS 8

// ---------------- dtype detection (edge_index int64 vs int32, mask u8 vs i32) ---------
__global__ void k_detect(const int* ei, const int* maskw, int* flags) {
  __shared__ int s_odd, s_maskhi;
  int t = threadIdx.x;
  if (t == 0) { s_odd = 0; s_maskhi = 0; }
  __syncthreads();
  int acc1 = 0;
  for (int i = t; i < 2048; i += blockDim.x) if (i & 1) acc1 |= ei[i];
  int acc2 = 0;
  for (int i = t; i < 256; i += blockDim.x) acc2 |= maskw[i] & 0xFFFFFF00;
  if (acc1) atomicOr(&s_odd, 1);
  if (acc2) atomicOr(&s_maskhi, 1);
  __syncthreads();
  if (t == 0) {
    flags[0] = (s_odd == 0) ? 1 : 0;     // 1 => edge_index stored as int64
    flags[1] = (s_maskhi == 0) ? 1 : 0;  // 1 => mask stored as int32, 0 => uint8
  }
}

__device__ __forceinline__ int ld_edge(const int* ei, int idx, int f64) {
  return f64 ? ei[2 * (long long)idx] : ei[idx];
}

// ---------------- degree count ----------------
__global__ void k_count(const int* ei, int E, int* cnt, const int* flags) {
  int e = blockIdx.x * blockDim.x + threadIdx.x;
  if (e >= E) return;
  int f64 = flags[0];
  int dst = ld_edge(ei, E + e, f64);
  atomicAdd(&cnt[dst], 1);
}

__global__ void k_dinv(const int* cnt, int N, float* dinv, float* dcs) {
  int n = blockIdx.x * blockDim.x + threadIdx.x;
  if (n >= N) return;
  float c = (float)cnt[n];
  dinv[n] = 1.0f / sqrtf(c + 1.0f);
  dcs[n] = (cnt[n] > 0) ? (1.0f / sqrtf(c)) : 0.0f;
}

// ---------------- exclusive prefix scan over cnt -> rowptr ----------------
__global__ void k_scan1(const int* cnt, int N, int* excl, int* bsum) {
  __shared__ int s[BS];
  int b = blockIdx.x, t = threadIdx.x;
  int base = b * SCAN_CHUNK + t * SCAN_ITEMS;
  int v[SCAN_ITEMS];
  int tsum = 0;
#pragma unroll
  for (int i = 0; i < SCAN_ITEMS; i++) {
    int idx = base + i;
    v[i] = (idx < N) ? cnt[idx] : 0;
    tsum += v[i];
  }
  s[t] = tsum;
  __syncthreads();
  for (int d = 1; d < BS; d <<= 1) {
    int add = (t >= d) ? s[t - d] : 0;
    __syncthreads();
    s[t] += add;
    __syncthreads();
  }
  int incl = s[t];
  int texcl = incl - tsum;
  if (t == BS - 1) bsum[b] = incl;
  int run = texcl;
#pragma unroll
  for (int i = 0; i < SCAN_ITEMS; i++) {
    int idx = base + i;
    if (idx < N) excl[idx] = run;
    run += v[i];
  }
}

__global__ void k_scan2(int* bsum, int nb) {
  if (threadIdx.x == 0 && blockIdx.x == 0) {
    int run = 0;
    for (int i = 0; i < nb; i++) { int v = bsum[i]; bsum[i] = run; run += v; }
  }
}

__global__ void k_scan3(int* rowptr, const int* bsum, int N, int E) {
  int i = blockIdx.x * blockDim.x + threadIdx.x;
  if (i < N) rowptr[i] += bsum[i / SCAN_CHUNK];
  if (i == 0) rowptr[N] = E;
}

// ---------------- CSR fill: csr[j] = src ----------------
__global__ void k_fill(const int* ei, int E, const int* rowptr, int* fill,
                       int* csr, const int* flags) {
  int e = blockIdx.x * blockDim.x + threadIdx.x;
  if (e >= E) return;
  int f64 = flags[0];
  int s_ = ld_edge(ei, e, f64);
  int d_ = ld_edge(ei, E + e, f64);
  int pos = rowptr[d_] + atomicAdd(&fill[d_], 1);
  csr[pos] = s_;
}

// ---------------- canonical mask ----------------
__global__ void k_mask(const void* maskp, const int* flags, int* mint, int N) {
  int n = blockIdx.x * blockDim.x + threadIdx.x;
  if (n >= N) return;
  int v = flags[1] ? ((const int*)maskp)[n] : (int)((const unsigned char*)maskp)[n];
  mint[n] = (v != 0) ? 1 : 0;
}

// ---------------- h0s = fp16( dinv[n] * (x @ W1) ) ----------------
__global__ void k_gemm1(const float* __restrict__ x, const float* __restrict__ W1,
                        const float* __restrict__ dinv, __half* __restrict__ h0s, int N) {
  __shared__ float Ws[64 * 64];
  __shared__ float xs[4][64];
  int t = threadIdx.x;
  for (int i = t; i < 4096; i += BS) Ws[i] = W1[i];
  int ty = t >> 6, c = t & 63;
  int row = blockIdx.x * 4 + ty;
  if (row < N) xs[ty][c] = x[row * 64 + c];
  __syncthreads();
  if (row >= N) return;
  float acc = 0.f;
#pragma unroll
  for (int k = 0; k < 64; k++) acc += xs[ty][k] * Ws[k * 64 + c];
  h0s[row * 64 + c] = __float2half(dinv[row] * acc);
}

// ---- conv1: h = relu(dinv[n]*(sum h0s[src] + h0s[n]) + b1); gs = dinv[n]*(h @ W2) ----
// one block (64 thr) per node; two edges per wave-iteration; half2 loads (2 ch/lane)
__global__ void __launch_bounds__(64) k_conv1(const __half* __restrict__ h0s,
                                              const int* __restrict__ csr,
                                              const int* __restrict__ rowptr,
                                              const float* __restrict__ dinv,
                                              const float* __restrict__ b1,
                                              const float* __restrict__ W2,
                                              float* __restrict__ gs, int N) {
  int n = blockIdx.x;
  int t = threadIdx.x;      // 0..63
  int half = t >> 5;        // which edge of the pair
  int cp = t & 31;          // channel pair: channels 2*cp, 2*cp+1
  int beg = rowptr[n], end = rowptr[n + 1];
  const __half2* h2 = (const __half2*)h0s;
  float a0 = 0.f, a1 = 0.f;
  for (int j = beg + half; j < end; j += 2) {
    int src = csr[j];
    float2 f = __half22float2(h2[src * 32 + cp]);
    a0 += f.x; a1 += f.y;
  }
  a0 += __shfl_xor(a0, 32);
  a1 += __shfl_xor(a1, 32);
  float2 sf = __half22float2(h2[n * 32 + cp]);
  float dn = dinv[n];
  float2 bb = ((const float2*)b1)[cp];
  float2 w2 = ((const float2*)W2)[cp];
  float v0 = dn * (a0 + sf.x) + bb.x;
  float v1 = dn * (a1 + sf.y) + bb.y;
  float tsum = fmaxf(v0, 0.f) * w2.x + fmaxf(v1, 0.f) * w2.y;
#pragma unroll
  for (int off = 16; off >= 1; off >>= 1) tsum += __shfl_xor(tsum, off);
  if (t == 0) gs[n] = dn * tsum;
}

// ---- conv2 + sigmoid + error + seed both sv buffers ----
__global__ void __launch_bounds__(PBS) k_conv2(const float* __restrict__ gs,
                                               const int* __restrict__ csr,
                                               const int* __restrict__ rowptr,
                                               const float* __restrict__ dinv,
                                               const float* __restrict__ dcs,
                                               const float* __restrict__ b2,
                                               const int* __restrict__ mint,
                                               const int* __restrict__ labels,
                                               float2* __restrict__ probs,
                                               float2* __restrict__ svA,
                                               float2* __restrict__ svB, int N) {
  int gid = blockIdx.x * PBS + threadIdx.x;
  int node = gid >> 4;
  int lane = gid & 15;
  if (node >= N) return;
  float s = 0.f;
  int beg = rowptr[node], end = rowptr[node + 1];
  for (int j = beg + lane; j < end; j += VEC) s += gs[csr[j]];
#pragma unroll
  for (int off = 8; off >= 1; off >>= 1) s += __shfl_xor(s, off);
  if (lane == 0) {
    float dn = dinv[node];
    float logit = dn * s + dn * gs[node] + b2[0];
    float p = 1.f / (1.f + expf(-logit));
    probs[node] = make_float2(1.f - p, p);
    float e0 = 0.f, e1 = 0.f;
    if (mint[node]) {
      int lab = labels[node];
      e0 = (lab == 0 ? 1.f : 0.f) - (1.f - p);
      e1 = (lab == 1 ? 1.f : 0.f) - p;
    }
    float d = dcs[node];
    float2 sv = make_float2(d * e0, d * e1);
    svA[node] = sv;   // seed: masked entries stay constant through all prop1 iters
    svB[node] = sv;
  }
}

// ---- label prop 1 (alpha=0.5, fix). LAST also computes y and seeds prop2 ----
template <bool LAST>
__global__ void __launch_bounds__(PBS) k_prop1(const float2* __restrict__ sv_in,
                                               float2* __restrict__ sv_out,
                                               const int* __restrict__ csr,
                                               const int* __restrict__ rowptr,
                                               const float* __restrict__ dcs,
                                               const int* __restrict__ mint,
                                               const float2* __restrict__ probs,
                                               const int* __restrict__ labels,
                                               float2* __restrict__ ybuf, int N) {
  int gid = blockIdx.x * PBS + threadIdx.x;
  int node = gid >> 4;
  int lane = gid & 15;
  if (node >= N) return;
  if (mint[node]) {
    if (LAST && lane == 0) {
      int lab = labels[node];
      float2 y = make_float2(lab == 0 ? 1.f : 0.f, lab == 1 ? 1.f : 0.f);
      ybuf[node] = y;
      float d = dcs[node];
      sv_out[node] = make_float2(d * y.x, d * y.y);
    }
    return;  // sv_out[masked] already correct (seeded in conv2, constant)
  }
  float s0 = 0.f, s1 = 0.f;
  int beg = rowptr[node], end = rowptr[node + 1];
  for (int j = beg + lane; j < end; j += VEC) {
    float2 t = sv_in[csr[j]];
    s0 += t.x; s1 += t.y;
  }
#pragma unroll
  for (int off = 8; off >= 1; off >>= 1) {
    s0 += __shfl_xor(s0, off);
    s1 += __shfl_xor(s1, off);
  }
  if (lane == 0) {
    float d = dcs[node];
    float o0 = 0.5f * d * s0, o1 = 0.5f * d * s1;   // res=0 for unmasked
    if (LAST) {
      float2 p = probs[node];
      float2 y = make_float2(p.x + o0, p.y + o1);   // corrected (SCALE=1)
      ybuf[node] = y;
      sv_out[node] = make_float2(d * y.x, d * y.y);
    } else {
      sv_out[node] = make_float2(d * o0, d * o1);
    }
  }
}

// ---- label prop 2 (alpha=0.8, clamp). LAST writes final log-odds ----
template <bool LAST>
__global__ void __launch_bounds__(PBS) k_prop2(const float2* __restrict__ sv_in,
                                               float2* __restrict__ sv_out,
                                               const int* __restrict__ csr,
                                               const int* __restrict__ rowptr,
                                               const float* __restrict__ dcs,
                                               const float2* __restrict__ ybuf,
                                               float* __restrict__ outlog, int N) {
  int gid = blockIdx.x * PBS + threadIdx.x;
  int node = gid >> 4;
  int lane = gid & 15;
  if (node >= N) return;
  float s0 = 0.f, s1 = 0.f;
  int beg = rowptr[node], end = rowptr[node + 1];
  for (int j = beg + lane; j < end; j += VEC) {
    float2 t = sv_in[csr[j]];
    s0 += t.x; s1 += t.y;
  }
#pragma unroll
  for (int off = 8; off >= 1; off >>= 1) {
    s0 += __shfl_xor(s0, off);
    s1 += __shfl_xor(s1, off);
  }
  if (lane == 0) {
    float d = dcs[node];
    float2 y = ybuf[node];
    float o0 = fminf(fmaxf(0.8f * d * s0 + 0.2f * y.x, 0.f), 1.f);
    float o1 = fminf(fmaxf(0.8f * d * s1 + 0.2f * y.y, 0.f), 1.f);
    if (LAST) {
      outlog[node] = logf(o1 + 1e-12f) - logf(o0 + 1e-12f);
    } else {
      sv_out[node] = make_float2(d * o0, d * o1);
    }
  }
}

// ---------------- host launcher ----------------
extern "C" void kernel_launch(void* const* d_in, const int* in_sizes, int n_in,
                              void* d_out, int out_size, void* d_ws, size_t ws_size,
                              hipStream_t stream) {
  const float* x = (const float*)d_in[0];
  const int* ei = (const int*)d_in[1];
  const void* maskp = d_in[2];
  const int* labels = (const int*)d_in[3];
  const float* W1 = (const float*)d_in[4];
  const float* b1 = (const float*)d_in[5];
  const float* W2 = (const float*)d_in[6];
  const float* b2 = (const float*)d_in[7];

  const int N = in_sizes[2];      // 100000
  const int E = in_sizes[1] / 2;  // 1600000

  char* w = (char*)d_ws;
  auto alloc = [&](size_t bytes) -> void* {
    void* p = (void*)w;
    w += (bytes + 255) & ~(size_t)255;
    return p;
  };
  int* flags = (int*)alloc(8);
  int* cnt = (int*)alloc((size_t)N * 4);
  int* fill = (int*)alloc((size_t)N * 4);
  int* rowptr = (int*)alloc((size_t)(N + 1) * 4);
  int* bsum = (int*)alloc(256 * 4);
  int* mint = (int*)alloc((size_t)N * 4);
  float* dinv = (float*)alloc((size_t)N * 4);
  float* dcs = (float*)alloc((size_t)N * 4);
  __half* h0s = (__half*)alloc((size_t)N * 64 * 2);
  float* gs = (float*)alloc((size_t)N * 4);
  float2* probs = (float2*)alloc((size_t)N * 8);
  float2* ybuf = (float2*)alloc((size_t)N * 8);
  float2* svA = (float2*)alloc((size_t)N * 8);
  float2* svB = (float2*)alloc((size_t)N * 8);
  int* csr = (int*)alloc((size_t)E * 4);

  const int gridN = (N + BS - 1) / BS;
  const int gridE = (E + BS - 1) / BS;
  const int gridP = (N * VEC + PBS - 1) / PBS;
  const int nb = (N + SCAN_CHUNK - 1) / SCAN_CHUNK;

  hipMemsetAsync(cnt, 0, (size_t)N * 4, stream);
  hipMemsetAsync(fill, 0, (size_t)N * 4, stream);

  k_detect<<<1, 256, 0, stream>>>(ei, (const int*)maskp, flags);
  k_count<<<gridE, BS, 0, stream>>>(ei, E, cnt, flags);
  k_dinv<<<gridN, BS, 0, stream>>>(cnt, N, dinv, dcs);
  k_scan1<<<nb, BS, 0, stream>>>(cnt, N, rowptr, bsum);
  k_scan2<<<1, 64, 0, stream>>>(bsum, nb);
  k_scan3<<<gridN, BS, 0, stream>>>(rowptr, bsum, N, E);
  k_fill<<<gridE, BS, 0, stream>>>(ei, E, rowptr, fill, csr, flags);
  k_mask<<<gridN, BS, 0, stream>>>(maskp, flags, mint, N);

  k_gemm1<<<(N + 3) / 4, BS, 0, stream>>>(x, W1, dinv, h0s, N);
  k_conv1<<<N, 64, 0, stream>>>(h0s, csr, rowptr, dinv, b1, W2, gs, N);
  k_conv2<<<gridP, PBS, 0, stream>>>(gs, csr, rowptr, dinv, dcs, b2, mint, labels,
                                     probs, svA, svB, N);

  float2* pin = svA;
  float2* pout = svB;
  for (int it = 0; it < 49; it++) {
    k_prop1<false><<<gridP, PBS, 0, stream>>>(pin, pout, csr, rowptr, dcs, mint,
                                              probs, labels, ybuf, N);
    float2* t = pin; pin = pout; pout = t;
  }
  k_prop1<true><<<gridP, PBS, 0, stream>>>(pin, pout, csr, rowptr, dcs, mint,
                                           probs, labels, ybuf, N);
  { float2* t = pin; pin = pout; pout = t; }
  for (int it = 0; it < 49; it++) {
    k_prop2<false><<<gridP, PBS, 0, stream>>>(pin, pout, csr, rowptr, dcs, ybuf,
                                              (float*)d_out, N);
    float2* t = pin; pin = pout; pout = t;
  }
  k_prop2<true><<<gridP, PBS, 0, stream>>>(pin, pout, csr, rowptr, dcs, ybuf,
                                           (float*)d_out, N);
}